// Round 5
// baseline (4812.668 us; speedup 1.0000x reference)
//
#include <hip/hip_runtime.h>
#include <hip/hip_bf16.h>

#define DEVFN __device__ __forceinline__

// ---------------- debug signal ----------------
__global__ void k_signal(float* out, float v) {
    if (threadIdx.x == 0 && blockIdx.x == 0) out[0] = v;
}

// ---------------- int-width detect + normalize ----------------
__global__ void k_detect64(const long long* __restrict__ p, int count, int* flag) {
    if (threadIdx.x == 0 && blockIdx.x == 0) {
        int ok = 1;
        for (int i = 0; i < count; i++) {
            long long v = p[i];
            if (v < 0 || v >= (1LL << 30)) { ok = 0; break; }
        }
        *flag = ok;
    }
}

__global__ __launch_bounds__(256) void k_cvt_idx(const void* __restrict__ p, int n,
                                                 const int* __restrict__ flag,
                                                 int* __restrict__ out) {
    int i = blockIdx.x * 256 + threadIdx.x;
    if (i >= n) return;
    if (*flag) out[i] = (int)((const long long*)p)[i];
    else       out[i] = ((const int*)p)[i];
}

// ---------------- FC1: h1 = relu(x @ w1 + b1), (128,128)@(128,512) ----------------
__global__ __launch_bounds__(256) void k_fc1(const float* __restrict__ x,
                                             const float* __restrict__ w,
                                             const float* __restrict__ b,
                                             float* __restrict__ out) {
    int j = blockIdx.x * 256 + threadIdx.x;   // 512
    int m = blockIdx.y;                       // 128
    float acc = b[j];
    const float* xr = x + m * 128;
    for (int k = 0; k < 128; k++)
        acc = fmaf(xr[k], w[k * 512 + j], acc);
    out[m * 512 + j] = fmaxf(acc, 0.f);
}

// ---------------- FC2: h = h1 @ w2 + b2, (128,512)@(512,110592) ----------------
__global__ __launch_bounds__(256) void k_fc2(const float* __restrict__ h1,
                                             const float* __restrict__ w,
                                             const float* __restrict__ bias,
                                             float* __restrict__ out) {
    const int N = 110592, K = 512, M = 128;
    int o = blockIdx.x * 256 + threadIdx.x;
    float bo = bias[o];
    for (int mc = 0; mc < M; mc += 32) {
        float acc[32];
#pragma unroll
        for (int i = 0; i < 32; i++) acc[i] = bo;
        for (int k = 0; k < K; k++) {
            float wv = w[(size_t)k * N + o];
#pragma unroll
            for (int i = 0; i < 32; i++)
                acc[i] = fmaf(h1[(mc + i) * K + k], wv, acc[i]);
        }
#pragma unroll
        for (int i = 0; i < 32; i++) out[(size_t)(mc + i) * N + o] = acc[i];
    }
}

// ---------------- graph build ----------------
__global__ __launch_bounds__(256) void k_zero_int(int* p, int n) {
    int i = blockIdx.x * 256 + threadIdx.x;
    if (i < n) p[i] = 0;
}

__global__ __launch_bounds__(256) void k_deg(const int* __restrict__ dst, int e,
                                             int* __restrict__ deg) {
    int i = blockIdx.x * 256 + threadIdx.x;
    if (i < e) atomicAdd(&deg[dst[i]], 1);
}

__global__ __launch_bounds__(256) void k_dinv(const int* __restrict__ deg,
                                              float* __restrict__ dinv, int n) {
    int i = blockIdx.x * 256 + threadIdx.x;
    if (i < n) dinv[i] = deg[i] > 0 ? 1.0f / sqrtf((float)deg[i]) : 0.0f;
}

// exclusive scan of deg[0..n) -> row_ptr[0..n], single block of 256 threads
__global__ __launch_bounds__(256) void k_scan(const int* __restrict__ deg,
                                              int* __restrict__ row_ptr, int n) {
    __shared__ int part[256];
    int tid = threadIdx.x;
    int per = (n + 255) / 256;
    int start = tid * per;
    int end = min(start + per, n);
    int s = 0;
    for (int i = start; i < end; i++) s += deg[i];
    part[tid] = s;
    __syncthreads();
    for (int off = 1; off < 256; off <<= 1) {
        int t = (tid >= off) ? part[tid - off] : 0;
        __syncthreads();
        part[tid] += t;
        __syncthreads();
    }
    int base = (tid == 0) ? 0 : part[tid - 1];
    int run = base;
    for (int i = start; i < end; i++) { row_ptr[i] = run; run += deg[i]; }
    if (tid == 255) row_ptr[n] = part[255];
}

__global__ __launch_bounds__(256) void k_fill(const int* __restrict__ src,
                                              const int* __restrict__ dst, int e,
                                              const int* __restrict__ row_ptr,
                                              int* __restrict__ cnt,
                                              const float* __restrict__ dinv,
                                              int* __restrict__ col, float* __restrict__ val) {
    int i = blockIdx.x * 256 + threadIdx.x;
    if (i >= e) return;
    int d = dst[i], s = src[i];
    int slot = row_ptr[d] + atomicAdd(&cnt[d], 1);
    col[slot] = s;
    val[slot] = -dinv[s] * dinv[d];
}

// ---------------- prop: out[b,d,c] = sum_j val[j]*h[b,col[j],c]; MODE1: 2*acc - sub ----------------
template <int CI, int MODE>
__global__ __launch_bounds__(256) void k_prop(const float* __restrict__ h,
                                              const float* __restrict__ sub,
                                              const int* __restrict__ row_ptr,
                                              const int* __restrict__ col,
                                              const float* __restrict__ val,
                                              float* __restrict__ out, int n) {
    constexpr int BY = 256 / CI;
    int c = threadIdx.x;
    int d = blockIdx.x;
    int b = blockIdx.y * BY + threadIdx.y;
    int p0 = row_ptr[d], p1 = row_ptr[d + 1];
    float acc = 0.f;
    const float* hb = h + (size_t)b * n * CI;
    for (int p = p0; p < p1; p++)
        acc = fmaf(val[p], hb[(size_t)col[p] * CI + c], acc);
    size_t oi = ((size_t)b * n + d) * CI + c;
    if (MODE) acc = 2.f * acc - sub[oi];
    out[oi] = acc;
}

// ---------------- cheb einsum + lrelu + repeat ----------------
template <int CI, int CO, int RT>
DEVFN void accum_term(const float* __restrict__ h, const float* __restrict__ Wt,
                      int j, float* acc) {
    for (int k = 0; k < CI; k++) {
        float wv = Wt[k * CO + j];
#pragma unroll
        for (int r = 0; r < RT; r++) acc[r] = fmaf(h[r * CI + k], wv, acc[r]);
    }
}

template <int CI, int CO, int RT, bool LRELU, bool REPEAT>
__global__ __launch_bounds__(256) void k_cheb_out(const float* __restrict__ t0,
                                                  const float* __restrict__ t1,
                                                  const float* __restrict__ t2,
                                                  const float* __restrict__ W,
                                                  const float* __restrict__ bias,
                                                  float* __restrict__ out, int n) {
    constexpr int YT = 256 / CO;
    constexpr int ROWS = YT * RT;
    int j = threadIdx.x;
    int m0 = blockIdx.x * ROWS + threadIdx.y * RT;
    float acc[RT];
    float bj = bias[j];
#pragma unroll
    for (int r = 0; r < RT; r++) acc[r] = bj;
    accum_term<CI, CO, RT>(t0 + (size_t)m0 * CI, W + 0 * CI * CO, j, acc);
    accum_term<CI, CO, RT>(t1 + (size_t)m0 * CI, W + 1 * CI * CO, j, acc);
    accum_term<CI, CO, RT>(t2 + (size_t)m0 * CI, W + 2 * CI * CO, j, acc);
#pragma unroll
    for (int r = 0; r < RT; r++) {
        float v = acc[r];
        if (LRELU) v = v >= 0.f ? v : 0.2f * v;
        int m = m0 + r;
        if (REPEAT) {
            int b = m / n, d = m % n;
            size_t o0 = ((size_t)b * (2 * n) + 2 * d) * CO + j;
            out[o0] = v;
            out[o0 + CO] = v;
        } else {
            out[(size_t)m * CO + j] = v;
        }
    }
}

// ---------------- final conv: ci=16, co=3, no lrelu/repeat ----------------
__global__ __launch_bounds__(256) void k_final_conv(const float* __restrict__ t0,
                                                    const float* __restrict__ t1,
                                                    const float* __restrict__ t2,
                                                    const float* __restrict__ W,
                                                    const float* __restrict__ bias,
                                                    float* __restrict__ out, int M) {
    int m = blockIdx.x * 256 + threadIdx.x;
    if (m >= M) return;
    float a0 = bias[0], a1 = bias[1], a2 = bias[2];
    const float* hs[3] = {t0, t1, t2};
#pragma unroll
    for (int t = 0; t < 3; t++) {
        const float* h = hs[t] + (size_t)m * 16;
        const float* Wt = W + t * 48;
#pragma unroll
        for (int k = 0; k < 16; k++) {
            float hv = h[k];
            a0 = fmaf(hv, Wt[k * 3 + 0], a0);
            a1 = fmaf(hv, Wt[k * 3 + 1], a1);
            a2 = fmaf(hv, Wt[k * 3 + 2], a2);
        }
    }
    out[(size_t)m * 3 + 0] = a0;
    out[(size_t)m * 3 + 1] = a1;
    out[(size_t)m * 3 + 2] = a2;
}

// ---------------- permute + slice + f32 store (reference output dtype is float32!) --------
__global__ __launch_bounds__(256) void k_permute(const float* __restrict__ h,
                                                 const int* __restrict__ perm,
                                                 float* __restrict__ out) {
    const int V = 6890, N = 6912;
    int idx = blockIdx.x * 256 + threadIdx.x;
    if (idx >= 128 * V * 3) return;
    int c = idx % 3;
    int t = idx / 3;
    int v = t % V;
    int b = t / V;
    int p = perm[v];
    out[idx] = h[((size_t)b * N + p) * 3 + c];
}

extern "C" void kernel_launch(void* const* d_in, const int* in_sizes, int n_in,
                              void* d_out, int out_size, void* d_ws, size_t ws_size,
                              hipStream_t stream) {
    float* out = (float*)d_out;

    // ---- remap inputs by UNIQUE element counts (immune to input ordering) ----
    static const int SIZES[20] = {
        16384, 65536, 512, 56623104, 110592,
        49152, 128, 24576, 64, 6144, 32, 1536, 16, 144, 3,
        10368, 20736, 41472, 82944, 6912
    };
    const void* in[20];
    bool map_ok = (n_in == 20);
    if (map_ok) {
        for (int s = 0; s < 20; s++) {
            int found = -1;
            for (int i = 0; i < n_in; i++)
                if (in_sizes[i] == SIZES[s]) { found = i; break; }
            if (found < 0) { map_ok = false; break; }
            in[s] = d_in[found];
        }
    }
    if (!map_ok)
        for (int i = 0; i < 20 && i < n_in; i++) in[i] = d_in[i];

    const float* x     = (const float*)in[0];
    const float* fc_w1 = (const float*)in[1];
    const float* fc_b1 = (const float*)in[2];
    const float* fc_w2 = (const float*)in[3];
    const float* fc_b2 = (const float*)in[4];
    const float* W0 = (const float*)in[5];
    const float* b0 = (const float*)in[6];
    const float* W1 = (const float*)in[7];
    const float* b1 = (const float*)in[8];
    const float* W2 = (const float*)in[9];
    const float* b2 = (const float*)in[10];
    const float* W3 = (const float*)in[11];
    const float* b3 = (const float*)in[12];
    const float* W4 = (const float*)in[13];
    const float* b4 = (const float*)in[14];

    const size_t SZ = 28311552;  // 128*1728*128 max buffer elems
    float* ws = (float*)d_ws;
    float* buf0 = ws;
    float* buf1 = ws + SZ;
    float* buf2 = ws + 2 * SZ;
    float* buf3 = ws + 3 * SZ;
    float* h1   = ws + 4 * SZ;           // 65536
    float* dinv = h1 + 65536;            // 6912
    float* val  = dinv + 6912;           // 41472
    int* ideg = (int*)(val + 41472);     // 6912
    int* rowp = ideg + 6912;             // 6913
    int* cnt  = rowp + 6913;             // 6912
    int* col  = cnt + 6912;              // 41472
    int* e0 = col + 41472;               // 10368
    int* e1 = e0 + 10368;                // 20736
    int* e2 = e1 + 20736;                // 41472
    int* e3 = e2 + 41472;                // 82944
    int* pm = e3 + 82944;                // 6912
    int* flag = pm + 6912;               // 1
    size_t needed = (char*)(flag + 1) - (char*)d_ws;
    if (ws_size < needed) {
        k_signal<<<1, 64, 0, stream>>>(out, 1000.0f);
        return;
    }

    // --- normalize integer inputs (int64 vs int32, decided on device) ---
    k_detect64<<<1, 64, 0, stream>>>((const long long*)in[15], 64, flag);
    k_cvt_idx<<<(10368 + 255) / 256, 256, 0, stream>>>(in[15], 10368, flag, e0);
    k_cvt_idx<<<(20736 + 255) / 256, 256, 0, stream>>>(in[16], 20736, flag, e1);
    k_cvt_idx<<<(41472 + 255) / 256, 256, 0, stream>>>(in[17], 41472, flag, e2);
    k_cvt_idx<<<(82944 + 255) / 256, 256, 0, stream>>>(in[18], 82944, flag, e3);
    k_cvt_idx<<<(6912 + 255) / 256, 256, 0, stream>>>(in[19], 6912, flag, pm);

    // FC1 + FC2
    k_fc1<<<dim3(2, 128), 256, 0, stream>>>(x, fc_w1, fc_b1, h1);
    k_fc2<<<432, 256, 0, stream>>>(h1, fc_w2, fc_b2, buf0);

    auto build = [&](const int* edge, int e, int n) {
        int nb_n = (n + 255) / 256, nb_e = (e + 255) / 256;
        k_zero_int<<<nb_n, 256, 0, stream>>>(ideg, n);
        k_zero_int<<<nb_n, 256, 0, stream>>>(cnt, n);
        k_deg<<<nb_e, 256, 0, stream>>>(edge + e, e, ideg);
        k_dinv<<<nb_n, 256, 0, stream>>>(ideg, dinv, n);
        k_scan<<<1, 256, 0, stream>>>(ideg, rowp, n);
        k_fill<<<nb_e, 256, 0, stream>>>(edge, edge + e, e, rowp, cnt, dinv, col, val);
    };

    // Layer 0: n=864, ci=128, co=128, in buf0 -> out buf3 (repeated to n=1728)
    build(e0, 6 * 864, 864);
    k_prop<128, 0><<<dim3(864, 64), dim3(128, 2), 0, stream>>>(buf0, buf0, rowp, col, val, buf1, 864);
    k_prop<128, 1><<<dim3(864, 64), dim3(128, 2), 0, stream>>>(buf1, buf0, rowp, col, val, buf2, 864);
    k_cheb_out<128, 128, 4, true, true><<<13824, dim3(128, 2), 0, stream>>>(buf0, buf1, buf2, W0, b0, buf3, 864);

    // Layer 1: n=1728, ci=128, co=64, in buf3 -> out buf0 (repeated to 3456)
    build(e1, 6 * 1728, 1728);
    k_prop<128, 0><<<dim3(1728, 64), dim3(128, 2), 0, stream>>>(buf3, buf3, rowp, col, val, buf1, 1728);
    k_prop<128, 1><<<dim3(1728, 64), dim3(128, 2), 0, stream>>>(buf1, buf3, rowp, col, val, buf2, 1728);
    k_cheb_out<128, 64, 4, true, true><<<13824, dim3(64, 4), 0, stream>>>(buf3, buf1, buf2, W1, b1, buf0, 1728);

    // Layer 2: n=3456, ci=64, co=32, in buf0 -> out buf3 (repeated to 6912)
    build(e2, 6 * 3456, 3456);
    k_prop<64, 0><<<dim3(3456, 32), dim3(64, 4), 0, stream>>>(buf0, buf0, rowp, col, val, buf1, 3456);
    k_prop<64, 1><<<dim3(3456, 32), dim3(64, 4), 0, stream>>>(buf1, buf0, rowp, col, val, buf2, 3456);
    k_cheb_out<64, 32, 4, true, true><<<13824, dim3(32, 8), 0, stream>>>(buf0, buf1, buf2, W2, b2, buf3, 3456);

    // Layer 3: n=6912, ci=32, co=16, lrelu but NO repeat (i<3 only)
    build(e3, 6 * 6912, 6912);
    k_prop<32, 0><<<dim3(6912, 16), dim3(32, 8), 0, stream>>>(buf3, buf3, rowp, col, val, buf1, 6912);
    k_prop<32, 1><<<dim3(6912, 16), dim3(32, 8), 0, stream>>>(buf1, buf3, rowp, col, val, buf2, 6912);
    k_cheb_out<32, 16, 4, true, false><<<13824, dim3(16, 16), 0, stream>>>(buf3, buf1, buf2, W3, b3, buf0, 6912);

    // Layer 4: n=6912, ci=16, co=3, reuse CSR of edge3
    k_prop<16, 0><<<dim3(6912, 8), dim3(16, 16), 0, stream>>>(buf0, buf0, rowp, col, val, buf1, 6912);
    k_prop<16, 1><<<dim3(6912, 8), dim3(16, 16), 0, stream>>>(buf1, buf0, rowp, col, val, buf2, 6912);
    k_final_conv<<<(884736 + 255) / 256, 256, 0, stream>>>(buf0, buf1, buf2, W4, b4, buf3, 884736);

    // Permute + slice, f32 output
    int tot = 128 * 6890 * 3;
    k_permute<<<(tot + 255) / 256, 256, 0, stream>>>(buf3, pm, out);

    if (!map_ok) k_signal<<<1, 64, 0, stream>>>(out, 2000.0f);
}

// Round 7
// 3242.352 us; speedup vs baseline: 1.4843x; 1.4843x over previous
//
#include <hip/hip_runtime.h>
#include <hip/hip_bf16.h>

#define DEVFN __device__ __forceinline__

// ---------------- debug signal ----------------
__global__ void k_signal(float* out, float v) {
    if (threadIdx.x == 0 && blockIdx.x == 0) out[0] = v;
}

// ---------------- int-width detect + normalize ----------------
__global__ void k_detect64(const long long* __restrict__ p, int count, int* flag) {
    if (threadIdx.x == 0 && blockIdx.x == 0) {
        int ok = 1;
        for (int i = 0; i < count; i++) {
            long long v = p[i];
            if (v < 0 || v >= (1LL << 30)) { ok = 0; break; }
        }
        *flag = ok;
    }
}

__global__ __launch_bounds__(256) void k_cvt_idx(const void* __restrict__ p, int n,
                                                 const int* __restrict__ flag,
                                                 int* __restrict__ out) {
    int i = blockIdx.x * 256 + threadIdx.x;
    if (i >= n) return;
    if (*flag) out[i] = (int)((const long long*)p)[i];
    else       out[i] = ((const int*)p)[i];
}

// ---------------- FC1: h1 = relu(x @ w1 + b1), (128,128)@(128,512) ----------------
__global__ __launch_bounds__(256) void k_fc1(const float* __restrict__ x,
                                             const float* __restrict__ w,
                                             const float* __restrict__ b,
                                             float* __restrict__ out) {
    int j = blockIdx.x * 256 + threadIdx.x;   // 512
    int m = blockIdx.y;                       // 128
    float acc = b[j];
    const float* xr = x + m * 128;
    for (int k = 0; k < 128; k++)
        acc = fmaf(xr[k], w[k * 512 + j], acc);
    out[m * 512 + j] = fmaxf(acc, 0.f);
}

// ---------------- FC2 tiled GEMM: (128,512)@(512,110592)+b ----------------
// block: 128 m-rows x 128 n-cols tile; thread: 8 m x 8 n (tx = n-lane, ty = m-group)
__global__ __launch_bounds__(256) void k_fc2_gemm(const float* __restrict__ h1,
                                                  const float* __restrict__ w,
                                                  const float* __restrict__ bias,
                                                  float* __restrict__ out) {
    const int N = 110592, K = 512;
    const int tx = threadIdx.x & 15;
    const int ty = threadIdx.x >> 4;
    const int jb = blockIdx.x * 128 + tx;   // j = jb + jj*16
    const int m0 = ty * 8;

    float acc[8][8];
#pragma unroll
    for (int jj = 0; jj < 8; jj++) {
        float bj = bias[jb + jj * 16];
#pragma unroll
        for (int r = 0; r < 8; r++) acc[r][jj] = bj;
    }
    for (int k = 0; k < K; k += 4) {
        float4 a[8];
#pragma unroll
        for (int r = 0; r < 8; r++)
            a[r] = *(const float4*)(h1 + (m0 + r) * K + k);
#pragma unroll
        for (int kk = 0; kk < 4; kk++) {
            float wv[8];
#pragma unroll
            for (int jj = 0; jj < 8; jj++)
                wv[jj] = w[(size_t)(k + kk) * N + jb + jj * 16];
#pragma unroll
            for (int r = 0; r < 8; r++) {
                float av = kk == 0 ? a[r].x : kk == 1 ? a[r].y : kk == 2 ? a[r].z : a[r].w;
#pragma unroll
                for (int jj = 0; jj < 8; jj++)
                    acc[r][jj] = fmaf(av, wv[jj], acc[r][jj]);
            }
        }
    }
#pragma unroll
    for (int r = 0; r < 8; r++)
#pragma unroll
        for (int jj = 0; jj < 8; jj++)
            out[(size_t)(m0 + r) * N + jb + jj * 16] = acc[r][jj];
}

// ---------------- graph build ----------------
__global__ __launch_bounds__(256) void k_zero_int(int* p, int n) {
    int i = blockIdx.x * 256 + threadIdx.x;
    if (i < n) p[i] = 0;
}

__global__ __launch_bounds__(256) void k_deg(const int* __restrict__ dst, int e,
                                             int* __restrict__ deg) {
    int i = blockIdx.x * 256 + threadIdx.x;
    if (i < e) atomicAdd(&deg[dst[i]], 1);
}

__global__ __launch_bounds__(256) void k_dinv(const int* __restrict__ deg,
                                              float* __restrict__ dinv, int n) {
    int i = blockIdx.x * 256 + threadIdx.x;
    if (i < n) dinv[i] = deg[i] > 0 ? 1.0f / sqrtf((float)deg[i]) : 0.0f;
}

// exclusive scan of deg[0..n) -> row_ptr[0..n], single block of 256 threads
__global__ __launch_bounds__(256) void k_scan(const int* __restrict__ deg,
                                              int* __restrict__ row_ptr, int n) {
    __shared__ int part[256];
    int tid = threadIdx.x;
    int per = (n + 255) / 256;
    int start = tid * per;
    int end = min(start + per, n);
    int s = 0;
    for (int i = start; i < end; i++) s += deg[i];
    part[tid] = s;
    __syncthreads();
    for (int off = 1; off < 256; off <<= 1) {
        int t = (tid >= off) ? part[tid - off] : 0;
        __syncthreads();
        part[tid] += t;
        __syncthreads();
    }
    int base = (tid == 0) ? 0 : part[tid - 1];
    int run = base;
    for (int i = start; i < end; i++) { row_ptr[i] = run; run += deg[i]; }
    if (tid == 255) row_ptr[n] = part[255];
}

__global__ __launch_bounds__(256) void k_fill(const int* __restrict__ src,
                                              const int* __restrict__ dst, int e,
                                              const int* __restrict__ row_ptr,
                                              int* __restrict__ cnt,
                                              const float* __restrict__ dinv,
                                              int* __restrict__ col, float* __restrict__ val) {
    int i = blockIdx.x * 256 + threadIdx.x;
    if (i >= e) return;
    int d = dst[i], s = src[i];
    int slot = row_ptr[d] + atomicAdd(&cnt[d], 1);
    col[slot] = s;
    val[slot] = -dinv[s] * dinv[d];
}

// ---------------- prop: out[b,d,c] = sum_j val[j]*h[b,col[j],c]; MODE1: 2*acc - sub ----------------
template <int CI, int MODE>
__global__ __launch_bounds__(256) void k_prop(const float* __restrict__ h,
                                              const float* __restrict__ sub,
                                              const int* __restrict__ row_ptr,
                                              const int* __restrict__ col,
                                              const float* __restrict__ val,
                                              float* __restrict__ out, int n) {
    constexpr int BY = 256 / CI;
    int c = threadIdx.x;
    int d = blockIdx.x;
    int b = blockIdx.y * BY + threadIdx.y;
    int p0 = row_ptr[d], p1 = row_ptr[d + 1];
    float acc = 0.f;
    const float* hb = h + (size_t)b * n * CI;
    for (int p = p0; p < p1; p++)
        acc = fmaf(val[p], hb[(size_t)col[p] * CI + c], acc);
    size_t oi = ((size_t)b * n + d) * CI + c;
    if (MODE) acc = 2.f * acc - sub[oi];
    out[oi] = acc;
}

// ---------------- cheb einsum as register-tiled GEMM ----------------
// C[M,CO] = sum_t Tt[M,CI] @ Wt[CI,CO] + bias, + lrelu, + optional repeat(2,axis=node)
// block: 128 rows x CO cols; thread: 8 rows x JT cols (JT = CO/16)
template <int CI, int CO, bool REPEAT>
__global__ __launch_bounds__(256) void k_cheb_gemm(const float* __restrict__ t0,
                                                   const float* __restrict__ t1,
                                                   const float* __restrict__ t2,
                                                   const float* __restrict__ W,
                                                   const float* __restrict__ bias,
                                                   float* __restrict__ out, int n) {
    constexpr int JT = CO / 16;
    const int tx = threadIdx.x & 15;
    const int ty = threadIdx.x >> 4;
    const int m_base = blockIdx.x * 128 + ty * 8;

    float acc[8][JT];
#pragma unroll
    for (int jj = 0; jj < JT; jj++) {
        float bj = bias[tx + jj * 16];
#pragma unroll
        for (int r = 0; r < 8; r++) acc[r][jj] = bj;
    }

    const float* As[3] = {t0, t1, t2};
#pragma unroll 1
    for (int t = 0; t < 3; t++) {
        const float* A = As[t] + (size_t)m_base * CI;
        const float* Wt = W + t * CI * CO;
        for (int k = 0; k < CI; k += 4) {
            float4 a[8];
#pragma unroll
            for (int r = 0; r < 8; r++)
                a[r] = *(const float4*)(A + r * CI + k);
#pragma unroll
            for (int kk = 0; kk < 4; kk++) {
                float wv[JT];
#pragma unroll
                for (int jj = 0; jj < JT; jj++)
                    wv[jj] = Wt[(k + kk) * CO + tx + jj * 16];
#pragma unroll
                for (int r = 0; r < 8; r++) {
                    float av = kk == 0 ? a[r].x : kk == 1 ? a[r].y : kk == 2 ? a[r].z : a[r].w;
#pragma unroll
                    for (int jj = 0; jj < JT; jj++)
                        acc[r][jj] = fmaf(av, wv[jj], acc[r][jj]);
                }
            }
        }
    }

#pragma unroll
    for (int r = 0; r < 8; r++) {
        int m = m_base + r;
        int b = m / n, d = m - b * n;   // used only if REPEAT
        size_t o0 = REPEAT ? ((size_t)b * (2 * n) + 2 * d) * CO : (size_t)m * CO;
#pragma unroll
        for (int jj = 0; jj < JT; jj++) {
            float v = acc[r][jj];
            v = v >= 0.f ? v : 0.2f * v;   // lrelu (all cheb GEMM layers use it)
            int j = tx + jj * 16;
            out[o0 + j] = v;
            if (REPEAT) out[o0 + CO + j] = v;
        }
    }
}

// ---------------- final conv: ci=16, co=3, no lrelu/repeat ----------------
__global__ __launch_bounds__(256) void k_final_conv(const float* __restrict__ t0,
                                                    const float* __restrict__ t1,
                                                    const float* __restrict__ t2,
                                                    const float* __restrict__ W,
                                                    const float* __restrict__ bias,
                                                    float* __restrict__ out, int M) {
    int m = blockIdx.x * 256 + threadIdx.x;
    if (m >= M) return;
    float a0 = bias[0], a1 = bias[1], a2 = bias[2];
    const float* hs[3] = {t0, t1, t2};
#pragma unroll
    for (int t = 0; t < 3; t++) {
        const float* h = hs[t] + (size_t)m * 16;
        const float* Wt = W + t * 48;
#pragma unroll
        for (int k = 0; k < 16; k++) {
            float hv = h[k];
            a0 = fmaf(hv, Wt[k * 3 + 0], a0);
            a1 = fmaf(hv, Wt[k * 3 + 1], a1);
            a2 = fmaf(hv, Wt[k * 3 + 2], a2);
        }
    }
    out[(size_t)m * 3 + 0] = a0;
    out[(size_t)m * 3 + 1] = a1;
    out[(size_t)m * 3 + 2] = a2;
}

// ---------------- permute + slice (f32 output) ----------------
__global__ __launch_bounds__(256) void k_permute(const float* __restrict__ h,
                                                 const int* __restrict__ perm,
                                                 float* __restrict__ out) {
    const int V = 6890, N = 6912;
    int idx = blockIdx.x * 256 + threadIdx.x;
    if (idx >= 128 * V * 3) return;
    int c = idx % 3;
    int t = idx / 3;
    int v = t % V;
    int b = t / V;
    int p = perm[v];
    out[idx] = h[((size_t)b * N + p) * 3 + c];
}

extern "C" void kernel_launch(void* const* d_in, const int* in_sizes, int n_in,
                              void* d_out, int out_size, void* d_ws, size_t ws_size,
                              hipStream_t stream) {
    float* out = (float*)d_out;

    // ---- remap inputs by UNIQUE element counts (immune to input ordering) ----
    static const int SIZES[20] = {
        16384, 65536, 512, 56623104, 110592,
        49152, 128, 24576, 64, 6144, 32, 1536, 16, 144, 3,
        10368, 20736, 41472, 82944, 6912
    };
    const void* in[20];
    bool map_ok = (n_in == 20);
    if (map_ok) {
        for (int s = 0; s < 20; s++) {
            int found = -1;
            for (int i = 0; i < n_in; i++)
                if (in_sizes[i] == SIZES[s]) { found = i; break; }
            if (found < 0) { map_ok = false; break; }
            in[s] = d_in[found];
        }
    }
    if (!map_ok)
        for (int i = 0; i < 20 && i < n_in; i++) in[i] = d_in[i];

    const float* x     = (const float*)in[0];
    const float* fc_w1 = (const float*)in[1];
    const float* fc_b1 = (const float*)in[2];
    const float* fc_w2 = (const float*)in[3];
    const float* fc_b2 = (const float*)in[4];
    const float* W0 = (const float*)in[5];
    const float* b0 = (const float*)in[6];
    const float* W1 = (const float*)in[7];
    const float* b1 = (const float*)in[8];
    const float* W2 = (const float*)in[9];
    const float* b2 = (const float*)in[10];
    const float* W3 = (const float*)in[11];
    const float* b3 = (const float*)in[12];
    const float* W4 = (const float*)in[13];
    const float* b4 = (const float*)in[14];

    const size_t SZ = 28311552;  // 128*1728*128 max buffer elems
    float* ws = (float*)d_ws;
    float* buf0 = ws;
    float* buf1 = ws + SZ;
    float* buf2 = ws + 2 * SZ;
    float* buf3 = ws + 3 * SZ;
    float* h1   = ws + 4 * SZ;           // 65536
    float* dinv = h1 + 65536;            // 6912
    float* val  = dinv + 6912;           // 41472
    int* ideg = (int*)(val + 41472);     // 6912
    int* rowp = ideg + 6912;             // 6913
    int* cnt  = rowp + 6913;             // 6912
    int* col  = cnt + 6912;              // 41472
    int* e0 = col + 41472;               // 10368
    int* e1 = e0 + 10368;                // 20736
    int* e2 = e1 + 20736;                // 41472
    int* e3 = e2 + 41472;                // 82944
    int* pm = e3 + 82944;                // 6912
    int* flag = pm + 6912;               // 1
    size_t needed = (char*)(flag + 1) - (char*)d_ws;
    if (ws_size < needed) {
        k_signal<<<1, 64, 0, stream>>>(out, 1000.0f);
        return;
    }

    // --- normalize integer inputs (int64 vs int32, decided on device) ---
    k_detect64<<<1, 64, 0, stream>>>((const long long*)in[15], 64, flag);
    k_cvt_idx<<<(10368 + 255) / 256, 256, 0, stream>>>(in[15], 10368, flag, e0);
    k_cvt_idx<<<(20736 + 255) / 256, 256, 0, stream>>>(in[16], 20736, flag, e1);
    k_cvt_idx<<<(41472 + 255) / 256, 256, 0, stream>>>(in[17], 41472, flag, e2);
    k_cvt_idx<<<(82944 + 255) / 256, 256, 0, stream>>>(in[18], 82944, flag, e3);
    k_cvt_idx<<<(6912 + 255) / 256, 256, 0, stream>>>(in[19], 6912, flag, pm);

    // FC1 + FC2
    k_fc1<<<dim3(2, 128), 256, 0, stream>>>(x, fc_w1, fc_b1, h1);
    k_fc2_gemm<<<864, 256, 0, stream>>>(h1, fc_w2, fc_b2, buf0);

    auto build = [&](const int* edge, int e, int n) {
        int nb_n = (n + 255) / 256, nb_e = (e + 255) / 256;
        k_zero_int<<<nb_n, 256, 0, stream>>>(ideg, n);
        k_zero_int<<<nb_n, 256, 0, stream>>>(cnt, n);
        k_deg<<<nb_e, 256, 0, stream>>>(edge + e, e, ideg);
        k_dinv<<<nb_n, 256, 0, stream>>>(ideg, dinv, n);
        k_scan<<<1, 256, 0, stream>>>(ideg, rowp, n);
        k_fill<<<nb_e, 256, 0, stream>>>(edge, edge + e, e, rowp, cnt, dinv, col, val);
    };

    // Layer 0: n=864, ci=128, co=128, in buf0 -> out buf3 (repeated to n=1728)
    build(e0, 6 * 864, 864);
    k_prop<128, 0><<<dim3(864, 64), dim3(128, 2), 0, stream>>>(buf0, buf0, rowp, col, val, buf1, 864);
    k_prop<128, 1><<<dim3(864, 64), dim3(128, 2), 0, stream>>>(buf1, buf0, rowp, col, val, buf2, 864);
    k_cheb_gemm<128, 128, true><<<864, 256, 0, stream>>>(buf0, buf1, buf2, W0, b0, buf3, 864);

    // Layer 1: n=1728, ci=128, co=64, in buf3 -> out buf0 (repeated to 3456)
    build(e1, 6 * 1728, 1728);
    k_prop<128, 0><<<dim3(1728, 64), dim3(128, 2), 0, stream>>>(buf3, buf3, rowp, col, val, buf1, 1728);
    k_prop<128, 1><<<dim3(1728, 64), dim3(128, 2), 0, stream>>>(buf1, buf3, rowp, col, val, buf2, 1728);
    k_cheb_gemm<128, 64, true><<<1728, 256, 0, stream>>>(buf3, buf1, buf2, W1, b1, buf0, 1728);

    // Layer 2: n=3456, ci=64, co=32, in buf0 -> out buf3 (repeated to 6912)
    build(e2, 6 * 3456, 3456);
    k_prop<64, 0><<<dim3(3456, 32), dim3(64, 4), 0, stream>>>(buf0, buf0, rowp, col, val, buf1, 3456);
    k_prop<64, 1><<<dim3(3456, 32), dim3(64, 4), 0, stream>>>(buf1, buf0, rowp, col, val, buf2, 3456);
    k_cheb_gemm<64, 32, true><<<3456, 256, 0, stream>>>(buf0, buf1, buf2, W2, b2, buf3, 3456);

    // Layer 3: n=6912, ci=32, co=16, lrelu but NO repeat (i<3 only)
    build(e3, 6 * 6912, 6912);
    k_prop<32, 0><<<dim3(6912, 16), dim3(32, 8), 0, stream>>>(buf3, buf3, rowp, col, val, buf1, 6912);
    k_prop<32, 1><<<dim3(6912, 16), dim3(32, 8), 0, stream>>>(buf1, buf3, rowp, col, val, buf2, 6912);
    k_cheb_gemm<32, 16, false><<<6912, 256, 0, stream>>>(buf3, buf1, buf2, W3, b3, buf0, 6912);

    // Layer 4: n=6912, ci=16, co=3, reuse CSR of edge3
    k_prop<16, 0><<<dim3(6912, 8), dim3(16, 16), 0, stream>>>(buf0, buf0, rowp, col, val, buf1, 6912);
    k_prop<16, 1><<<dim3(6912, 8), dim3(16, 16), 0, stream>>>(buf1, buf0, rowp, col, val, buf2, 6912);
    k_final_conv<<<(884736 + 255) / 256, 256, 0, stream>>>(buf0, buf1, buf2, W4, b4, buf3, 884736);

    // Permute + slice, f32 output
    int tot = 128 * 6890 * 3;
    k_permute<<<(tot + 255) / 256, 256, 0, stream>>>(buf3, pm, out);

    if (!map_ok) k_signal<<<1, 64, 0, stream>>>(out, 2000.0f);
}